// Round 1
// baseline (380.809 us; speedup 1.0000x reference)
//
#include <hip/hip_runtime.h>
#include <cstdint>
#include <cstddef>

#define BSZ 256
#define NN 500
#define D 512
#define H 16
#define KSTRIDE 1536
#define NP 516            // padded LDS stride (516 % 32 == 4 -> conflict-free head writes)
#define NEG_INF -1000000000.0f

// ---------------------------------------------------------------------------
// Transpose both 512x512 weight matrices into ws so GEMV reads are coalesced.
// grid (16,16,2), block (32,8)
// ---------------------------------------------------------------------------
__global__ __launch_bounds__(256) void transpose512(
    const float* __restrict__ W0, const float* __restrict__ Wf,
    float* __restrict__ Wt0, float* __restrict__ Wtf)
{
    __shared__ float tile[32][33];
    const float* in = blockIdx.z ? Wf : W0;
    float* out      = blockIdx.z ? Wtf : Wt0;
    const int bx = blockIdx.x * 32, by = blockIdx.y * 32;
    const int tx = threadIdx.x, ty = threadIdx.y;
#pragma unroll
    for (int i = 0; i < 32; i += 8)
        tile[ty + i][tx] = in[(size_t)(by + ty + i) * D + bx + tx];
    __syncthreads();
#pragma unroll
    for (int i = 0; i < 32; i += 8)
        out[(size_t)(bx + ty + i) * D + by + tx] = tile[tx][ty + i];
}

// ---------------------------------------------------------------------------
// One block per batch element. 1024 threads (16 waves).
// Pass 1: scores[h][n] = (q_h . K_h[n]) / sqrt(32)     (float4, coalesced)
// Pass 2: per-head softmax stats (1 wave per head)
// Pass 3: out[h*32+d] = sum_n w[h][n] * V[n][h*32+d]   (float4, coalesced)
// Pass 4: q_out = out @ W0^T + b0   (Wt pre-transposed, coalesced j)
// ---------------------------------------------------------------------------
__global__ __launch_bounds__(1024) void attn_layer(
    const float* __restrict__ q_in,
    const float* __restrict__ Katt,
    const float* __restrict__ Vatt,
    const unsigned char* __restrict__ mask,
    const float* __restrict__ Wt,
    const float* __restrict__ bias,
    float* __restrict__ q_out,
    int loff)
{
    __shared__ float p_lds[H * NP];                    // ~33 KB scores -> weights
    __shared__ __align__(16) float partial[8 * D];     // 16 KB cross-group reduce
    __shared__ float out_lds[D];
    __shared__ float inv_lds[H];

    const int b = blockIdx.x;
    const int t = threadIdx.x;
    const int r = t & 127;        // position within a 512-float row (x4)
    const int g = t >> 7;         // row group: 8 nodes processed per sweep
    const int h8 = r >> 3;        // head owning dims [r*4, r*4+3]

    const float4 q4 = *reinterpret_cast<const float4*>(q_in + (size_t)b * D + r * 4);

    const float* Kb = Katt + (size_t)b * NN * KSTRIDE + loff;
    const float* Vb = Vatt + (size_t)b * NN * KSTRIDE + loff;
    const unsigned char* mb = mask + (size_t)b * NN;

    // ---- Pass 1: scores --------------------------------------------------
    for (int n = g; n < NN; n += 8) {
        const float4 k4 = *reinterpret_cast<const float4*>(Kb + (size_t)n * KSTRIDE + r * 4);
        float s = q4.x * k4.x + q4.y * k4.y + q4.z * k4.z + q4.w * k4.w;
        s += __shfl_xor(s, 1);
        s += __shfl_xor(s, 2);
        s += __shfl_xor(s, 4);
        if ((r & 7) == 0) {
            float sc = s * 0.17677669529663687f;   // 1/sqrt(32)
            if (mb[n]) sc = NEG_INF;
            p_lds[h8 * NP + n] = sc;
        }
    }
    __syncthreads();

    // ---- Pass 2: per-head softmax, 1 wave per head ------------------------
    {
        const int h = t >> 6;
        const int j = t & 63;
        float m = -3.4e38f;
        for (int n = j; n < NN; n += 64) m = fmaxf(m, p_lds[h * NP + n]);
#pragma unroll
        for (int o = 1; o < 64; o <<= 1) m = fmaxf(m, __shfl_xor(m, o));
        float ssum = 0.f;
        for (int n = j; n < NN; n += 64) {
            const float e = __expf(p_lds[h * NP + n] - m);
            p_lds[h * NP + n] = e;
            ssum += e;
        }
#pragma unroll
        for (int o = 1; o < 64; o <<= 1) ssum += __shfl_xor(ssum, o);
        if (j == 0) inv_lds[h] = 1.0f / ssum;
    }
    __syncthreads();

    // ---- Pass 3: PV accumulate -------------------------------------------
    {
        float4 acc = {0.f, 0.f, 0.f, 0.f};
        for (int n = g; n < NN; n += 8) {
            const float w = p_lds[h8 * NP + n];
            const float4 v4 = *reinterpret_cast<const float4*>(Vb + (size_t)n * KSTRIDE + r * 4);
            acc.x += w * v4.x; acc.y += w * v4.y; acc.z += w * v4.z; acc.w += w * v4.w;
        }
        *reinterpret_cast<float4*>(partial + g * D + r * 4) = acc;
    }
    __syncthreads();
    if (t < D) {
        float o = 0.f;
#pragma unroll
        for (int g2 = 0; g2 < 8; ++g2) o += partial[g2 * D + t];
        out_lds[t] = o * inv_lds[t >> 5];
    }
    __syncthreads();

    // ---- Pass 4: GEMV q_out = out @ W^T + bias ----------------------------
    {
        const int j = t & 511;
        const int half = t >> 9;                 // split K-dim across thread halves
        const float* Wp = Wt + (size_t)half * 256 * D + j;
        const float* a  = out_lds + half * 256;
        float acc = 0.f;
#pragma unroll 4
        for (int k = 0; k < 256; ++k)
            acc += a[k] * Wp[(size_t)k * D];
        partial[half * D + j] = acc;
    }
    __syncthreads();
    if (t < D)
        q_out[(size_t)b * D + t] = partial[t] + partial[D + t] + bias[t];
}

// ---------------------------------------------------------------------------
// Final layer: q_final = q2 @ Wqf^T + bqf; single-head scores over K layer 2;
// s = 10*tanh(s/sqrt(512)); mask; softmax -> output weights (256 x 500).
// ---------------------------------------------------------------------------
__global__ __launch_bounds__(1024) void final_layer(
    const float* __restrict__ q_in,
    const float* __restrict__ Katt,
    const unsigned char* __restrict__ mask,
    const float* __restrict__ Wt,
    const float* __restrict__ bias,
    float* __restrict__ out)
{
    __shared__ float a_lds[D];
    __shared__ __align__(16) float qf_lds[D];
    __shared__ float part2[2 * D];
    __shared__ float s_lds[NN];
    __shared__ float red[16];
    __shared__ float bm, bs;

    const int b = blockIdx.x;
    const int t = threadIdx.x;

    if (t < D) a_lds[t] = q_in[(size_t)b * D + t];
    __syncthreads();

    // GEMV q_final = a @ Wqf^T + bqf
    {
        const int j = t & 511;
        const int half = t >> 9;
        const float* Wp = Wt + (size_t)half * 256 * D + j;
        const float* a  = a_lds + half * 256;
        float acc = 0.f;
#pragma unroll 4
        for (int k = 0; k < 256; ++k)
            acc += a[k] * Wp[(size_t)k * D];
        part2[half * D + j] = acc;
    }
    __syncthreads();
    if (t < D) qf_lds[t] = part2[t] + part2[D + t] + bias[t];
    __syncthreads();

    // scores: one wave per node, 8 floats per lane
    const int wv = t >> 6;
    const int l  = t & 63;
    const float4 qa = *reinterpret_cast<const float4*>(qf_lds + l * 8);
    const float4 qb = *reinterpret_cast<const float4*>(qf_lds + l * 8 + 4);
    const float* Kb = Katt + (size_t)b * NN * KSTRIDE + 1024;
    const unsigned char* mb = mask + (size_t)b * NN;

    for (int n = wv; n < NN; n += 16) {
        const float* kr = Kb + (size_t)n * KSTRIDE + l * 8;
        const float4 ka  = *reinterpret_cast<const float4*>(kr);
        const float4 kb4 = *reinterpret_cast<const float4*>(kr + 4);
        float s = qa.x * ka.x + qa.y * ka.y + qa.z * ka.z + qa.w * ka.w
                + qb.x * kb4.x + qb.y * kb4.y + qb.z * kb4.z + qb.w * kb4.w;
#pragma unroll
        for (int o = 1; o < 64; o <<= 1) s += __shfl_xor(s, o);
        if (l == 0) {
            float sc = 10.0f * tanhf(s * 0.044194173824159216f);  // clip(10*tanh)
            if (mb[n]) sc = NEG_INF;
            s_lds[n] = sc;
        }
    }
    __syncthreads();

    // block softmax over 500
    const float v = (t < NN) ? s_lds[t] : -3.4e38f;
    float m = v;
#pragma unroll
    for (int o = 1; o < 64; o <<= 1) m = fmaxf(m, __shfl_xor(m, o));
    if (l == 0) red[wv] = m;
    __syncthreads();
    if (t == 0) {
        float mm = red[0];
#pragma unroll
        for (int i = 1; i < 16; ++i) mm = fmaxf(mm, red[i]);
        bm = mm;
    }
    __syncthreads();
    const float e = (t < NN) ? __expf(v - bm) : 0.f;
    float ssum = e;
#pragma unroll
    for (int o = 1; o < 64; o <<= 1) ssum += __shfl_xor(ssum, o);
    if (l == 0) red[wv] = ssum;
    __syncthreads();
    if (t == 0) {
        float s2 = 0.f;
#pragma unroll
        for (int i = 0; i < 16; ++i) s2 += red[i];
        bs = 1.0f / s2;
    }
    __syncthreads();
    if (t < NN) out[(size_t)b * NN + t] = e * bs;
}

// ---------------------------------------------------------------------------
extern "C" void kernel_launch(void* const* d_in, const int* in_sizes, int n_in,
                              void* d_out, int out_size, void* d_ws, size_t ws_size,
                              hipStream_t stream) {
    const float* query = (const float*)d_in[0];
    const float* Katt  = (const float*)d_in[1];
    const float* Vatt  = (const float*)d_in[2];
    const unsigned char* mask = (const unsigned char*)d_in[3];
    const float* W0w = (const float*)d_in[4];
    const float* W0b = (const float*)d_in[5];
    const float* Wfw = (const float*)d_in[6];
    const float* Wfb = (const float*)d_in[7];

    float* out = (float*)d_out;
    float* ws  = (float*)d_ws;
    float* q1  = ws;                 // 256*512
    float* q2  = ws + 131072;        // 256*512
    float* Wt0 = ws + 262144;        // 512*512
    float* Wtf = ws + 524288;        // 512*512  (total 3 MB)

    transpose512<<<dim3(16, 16, 2), dim3(32, 8), 0, stream>>>(W0w, Wfw, Wt0, Wtf);
    attn_layer<<<BSZ, 1024, 0, stream>>>(query, Katt, Vatt, mask, Wt0, W0b, q1, 0);
    attn_layer<<<BSZ, 1024, 0, stream>>>(q1,    Katt, Vatt, mask, Wt0, W0b, q2, 512);
    final_layer<<<BSZ, 1024, 0, stream>>>(q2, Katt, mask, Wtf, Wfb, out);
}

// Round 2
// 309.439 us; speedup vs baseline: 1.2306x; 1.2306x over previous
//
#include <hip/hip_runtime.h>
#include <cstdint>
#include <cstddef>

#define BSZ 256
#define NN 500
#define D 512
#define H 16
#define KSTRIDE 1536
#define NEG_INF -1000000000.0f

// ---------------------------------------------------------------------------
// Transpose both 512x512 weight matrices into ws so GEMV reads are coalesced.
// grid (16,16,2), block (32,8)
// ---------------------------------------------------------------------------
__global__ __launch_bounds__(256) void transpose512(
    const float* __restrict__ W0, const float* __restrict__ Wf,
    float* __restrict__ Wt0, float* __restrict__ Wtf)
{
    __shared__ float tile[32][33];
    const float* in = blockIdx.z ? Wf : W0;
    float* out      = blockIdx.z ? Wtf : Wt0;
    const int bx = blockIdx.x * 32, by = blockIdx.y * 32;
    const int tx = threadIdx.x, ty = threadIdx.y;
#pragma unroll
    for (int i = 0; i < 32; i += 8)
        tile[ty + i][tx] = in[(size_t)(by + ty + i) * D + bx + tx];
    __syncthreads();
#pragma unroll
    for (int i = 0; i < 32; i += 8)
        out[(size_t)(bx + ty + i) * D + by + tx] = tile[tx][ty + i];
}

// ---------------------------------------------------------------------------
// Fused online-softmax attention layer + output GEMV.
// One block (1024 threads = 16 waves) per batch element.
// Each wave owns rows n ≡ wave (mod 16); each lane owns 8 dims (r*8..r*8+7),
// so one head (32 dims) = 4 lanes. Single sweep reads K row + V row together,
// maintaining running (m, l, acc) per head — no mid-kernel memory-idle phase.
// ---------------------------------------------------------------------------
__global__ __launch_bounds__(1024) void attn_layer_fused(
    const float* __restrict__ q_in,
    const float* __restrict__ Katt,
    const float* __restrict__ Vatt,
    const unsigned char* __restrict__ mask,
    const float* __restrict__ Wt,
    const float* __restrict__ bias,
    float* __restrict__ q_out,
    int loff)
{
    __shared__ __align__(16) float part_acc[16 * D];   // 32 KB partial PV accums
    __shared__ float part_m[16 * H];                   // per (group, head) running max
    __shared__ float part_l[16 * H];                   // per (group, head) running sum
    __shared__ __align__(16) float out_lds[D];
    __shared__ float gemv_part[2 * D];

    const int b = blockIdx.x;
    const int t = threadIdx.x;
    const int r = t & 63;     // lane: owns dims [r*8, r*8+8)
    const int g = t >> 6;     // wave id = row group (16 rows in flight)

    const float* qp = q_in + (size_t)b * D + r * 8;
    const float4 qa = *reinterpret_cast<const float4*>(qp);
    const float4 qb = *reinterpret_cast<const float4*>(qp + 4);

    const float* Kb = Katt + (size_t)b * NN * KSTRIDE + loff;
    const float* Vb = Vatt + (size_t)b * NN * KSTRIDE + loff;
    const unsigned char* mb = mask + (size_t)b * NN;

    float m = -3.4e38f, lsum = 0.f;
    float4 acc0 = {0.f, 0.f, 0.f, 0.f};
    float4 acc1 = {0.f, 0.f, 0.f, 0.f};

#pragma unroll 2
    for (int n = g; n < NN; n += 16) {
        const float* kr = Kb + (size_t)n * KSTRIDE + r * 8;
        const float* vr = Vb + (size_t)n * KSTRIDE + r * 8;
        const float4 ka  = *reinterpret_cast<const float4*>(kr);
        const float4 kb4 = *reinterpret_cast<const float4*>(kr + 4);
        const float4 va  = *reinterpret_cast<const float4*>(vr);
        const float4 vb4 = *reinterpret_cast<const float4*>(vr + 4);

        float s = qa.x * ka.x + qa.y * ka.y + qa.z * ka.z + qa.w * ka.w
                + qb.x * kb4.x + qb.y * kb4.y + qb.z * kb4.z + qb.w * kb4.w;
        s += __shfl_xor(s, 1);             // 4-lane reduce: one head
        s += __shfl_xor(s, 2);
        float sc = s * 0.17677669529663687f;   // 1/sqrt(32)
        if (mb[n]) sc = NEG_INF;

        const float mn   = fmaxf(m, sc);
        const float corr = __expf(m - mn);     // first iter: exp(-3.4e38-sc)=0
        const float e    = __expf(sc - mn);
        lsum = lsum * corr + e;
        acc0.x = acc0.x * corr + e * va.x;
        acc0.y = acc0.y * corr + e * va.y;
        acc0.z = acc0.z * corr + e * va.z;
        acc0.w = acc0.w * corr + e * va.w;
        acc1.x = acc1.x * corr + e * vb4.x;
        acc1.y = acc1.y * corr + e * vb4.y;
        acc1.z = acc1.z * corr + e * vb4.z;
        acc1.w = acc1.w * corr + e * vb4.w;
        m = mn;
    }

    *reinterpret_cast<float4*>(part_acc + g * D + r * 8)     = acc0;
    *reinterpret_cast<float4*>(part_acc + g * D + r * 8 + 4) = acc1;
    if ((r & 3) == 0) {
        part_m[g * H + (r >> 2)] = m;
        part_l[g * H + (r >> 2)] = lsum;
    }
    __syncthreads();

    // ---- combine the 16 groups' online-softmax states ----------------------
    if (t < D) {
        const int hd = t >> 5;
        float ms = -3.4e38f;
#pragma unroll
        for (int g2 = 0; g2 < 16; ++g2)
            ms = fmaxf(ms, part_m[g2 * H + hd]);
        float ls = 0.f, o = 0.f;
#pragma unroll
        for (int g2 = 0; g2 < 16; ++g2) {
            const float w = __expf(part_m[g2 * H + hd] - ms);
            ls += part_l[g2 * H + hd] * w;
            o  += part_acc[g2 * D + t] * w;
        }
        out_lds[t] = o / ls;
    }
    __syncthreads();

    // ---- GEMV q_out = out @ W^T + bias --------------------------------------
    {
        const int j = t & 511;
        const int half = t >> 9;                 // split K-dim across halves
        const float* Wp = Wt + (size_t)half * 256 * D + j;
        const float* a  = out_lds + half * 256;
        float acc = 0.f;
#pragma unroll 4
        for (int k = 0; k < 256; ++k)
            acc += a[k] * Wp[(size_t)k * D];
        gemv_part[half * D + j] = acc;
    }
    __syncthreads();
    if (t < D)
        q_out[(size_t)b * D + t] = gemv_part[t] + gemv_part[D + t] + bias[t];
}

// ---------------------------------------------------------------------------
// Final layer: q_final = q2 @ Wqf^T + bqf; 1-head scores over K layer 2;
// s = 10*tanh(s/sqrt(512)); mask; softmax -> output weights (256 x 500).
// 32 lanes per node -> 32 rows in flight per block.
// ---------------------------------------------------------------------------
__global__ __launch_bounds__(1024) void final_layer(
    const float* __restrict__ q_in,
    const float* __restrict__ Katt,
    const unsigned char* __restrict__ mask,
    const float* __restrict__ Wt,
    const float* __restrict__ bias,
    float* __restrict__ out)
{
    __shared__ float a_lds[D];
    __shared__ __align__(16) float qf_lds[D];
    __shared__ float part2[2 * D];
    __shared__ float s_lds[NN];
    __shared__ float red[16];
    __shared__ float bm, bs;

    const int b = blockIdx.x;
    const int t = threadIdx.x;

    if (t < D) a_lds[t] = q_in[(size_t)b * D + t];
    __syncthreads();

    // GEMV q_final = a @ Wqf^T + bqf
    {
        const int j = t & 511;
        const int half = t >> 9;
        const float* Wp = Wt + (size_t)half * 256 * D + j;
        const float* a  = a_lds + half * 256;
        float acc = 0.f;
#pragma unroll 4
        for (int k = 0; k < 256; ++k)
            acc += a[k] * Wp[(size_t)k * D];
        part2[half * D + j] = acc;
    }
    __syncthreads();
    if (t < D) qf_lds[t] = part2[t] + part2[D + t] + bias[t];
    __syncthreads();

    // scores: 32 lanes per node (16 floats per lane), 32 nodes in flight
    const int wv   = t >> 6;
    const int l    = t & 63;
    const int half = l >> 5;
    const int l32  = l & 31;

    const float* qpp = qf_lds + l32 * 16;
    const float4 q0 = *reinterpret_cast<const float4*>(qpp);
    const float4 q1 = *reinterpret_cast<const float4*>(qpp + 4);
    const float4 q2 = *reinterpret_cast<const float4*>(qpp + 8);
    const float4 q3 = *reinterpret_cast<const float4*>(qpp + 12);

    const float* Kb = Katt + (size_t)b * NN * KSTRIDE + 1024;
    const unsigned char* mb = mask + (size_t)b * NN;

    for (int n = wv * 2 + half; n < NN; n += 32) {
        const float* kr = Kb + (size_t)n * KSTRIDE + l32 * 16;
        const float4 k0 = *reinterpret_cast<const float4*>(kr);
        const float4 k1 = *reinterpret_cast<const float4*>(kr + 4);
        const float4 k2 = *reinterpret_cast<const float4*>(kr + 8);
        const float4 k3 = *reinterpret_cast<const float4*>(kr + 12);
        float s = q0.x * k0.x + q0.y * k0.y + q0.z * k0.z + q0.w * k0.w
                + q1.x * k1.x + q1.y * k1.y + q1.z * k1.z + q1.w * k1.w
                + q2.x * k2.x + q2.y * k2.y + q2.z * k2.z + q2.w * k2.w
                + q3.x * k3.x + q3.y * k3.y + q3.z * k3.z + q3.w * k3.w;
#pragma unroll
        for (int o = 1; o < 32; o <<= 1) s += __shfl_xor(s, o);
        if (l32 == 0) {
            float sc = 10.0f * tanhf(s * 0.044194173824159216f);  // 10*tanh(s/sqrt(512))
            if (mb[n]) sc = NEG_INF;
            s_lds[n] = sc;
        }
    }
    __syncthreads();

    // block softmax over 500
    const float v = (t < NN) ? s_lds[t] : -3.4e38f;
    float m = v;
#pragma unroll
    for (int o = 1; o < 64; o <<= 1) m = fmaxf(m, __shfl_xor(m, o));
    if (l == 0) red[wv] = m;
    __syncthreads();
    if (t == 0) {
        float mm = red[0];
#pragma unroll
        for (int i = 1; i < 16; ++i) mm = fmaxf(mm, red[i]);
        bm = mm;
    }
    __syncthreads();
    const float e = (t < NN) ? __expf(v - bm) : 0.f;
    float ssum = e;
#pragma unroll
    for (int o = 1; o < 64; o <<= 1) ssum += __shfl_xor(ssum, o);
    if (l == 0) red[wv] = ssum;
    __syncthreads();
    if (t == 0) {
        float s2 = 0.f;
#pragma unroll
        for (int i = 0; i < 16; ++i) s2 += red[i];
        bs = 1.0f / s2;
    }
    __syncthreads();
    if (t < NN) out[(size_t)b * NN + t] = e * bs;
}

// ---------------------------------------------------------------------------
extern "C" void kernel_launch(void* const* d_in, const int* in_sizes, int n_in,
                              void* d_out, int out_size, void* d_ws, size_t ws_size,
                              hipStream_t stream) {
    const float* query = (const float*)d_in[0];
    const float* Katt  = (const float*)d_in[1];
    const float* Vatt  = (const float*)d_in[2];
    const unsigned char* mask = (const unsigned char*)d_in[3];
    const float* W0w = (const float*)d_in[4];
    const float* W0b = (const float*)d_in[5];
    const float* Wfw = (const float*)d_in[6];
    const float* Wfb = (const float*)d_in[7];

    float* out = (float*)d_out;
    float* ws  = (float*)d_ws;
    float* q1  = ws;                 // 256*512
    float* q2  = ws + 131072;        // 256*512
    float* Wt0 = ws + 262144;        // 512*512
    float* Wtf = ws + 524288;        // 512*512  (total 3 MB)

    transpose512<<<dim3(16, 16, 2), dim3(32, 8), 0, stream>>>(W0w, Wfw, Wt0, Wtf);
    attn_layer_fused<<<BSZ, 1024, 0, stream>>>(query, Katt, Vatt, mask, Wt0, W0b, q1, 0);
    attn_layer_fused<<<BSZ, 1024, 0, stream>>>(q1,    Katt, Vatt, mask, Wt0, W0b, q2, 512);
    final_layer<<<BSZ, 1024, 0, stream>>>(q2, Katt, mask, Wtf, Wfb, out);
}